// Round 1
// baseline (7474.552 us; speedup 1.0000x reference)
//
#include <hip/hip_runtime.h>
#include <hip/hip_bf16.h>
#include <math.h>

#define DM     768
#define S_LEN  4096
#define NH     12
#define HD     64
#define DFF    3072
#define NLAYER 6
#define WIN    512

// ---------------- block reduction helper ----------------
__device__ inline float block_reduce_sum(float v, float* sbuf) {
#pragma unroll
  for (int off = 32; off > 0; off >>= 1) v += __shfl_down(v, off, 64);
  int lane = threadIdx.x & 63;
  int wid  = threadIdx.x >> 6;
  if (lane == 0) sbuf[wid] = v;
  __syncthreads();
  float r;
  if (threadIdx.x == 0) {
    r = 0.f;
    int nw = blockDim.x >> 6;
    for (int i = 0; i < nw; i++) r += sbuf[i];
    sbuf[0] = r;
  }
  __syncthreads();
  r = sbuf[0];
  __syncthreads();  // allow sbuf reuse by a following reduction
  return r;
}

// ---------------- embedding + layernorm ----------------
__global__ __launch_bounds__(256) void embed_ln_kernel(
    const int* __restrict__ tokens, const float* __restrict__ emb_tok,
    const float* __restrict__ emb_pos, const float* __restrict__ gs,
    const float* __restrict__ gb, float* __restrict__ x) {
  __shared__ float sbuf[8];
  int s = blockIdx.x;
  int tok = tokens[s];
  const float* et = emb_tok + (size_t)tok * DM;
  const float* ep = emb_pos + (size_t)s * DM;
  float v[3];
  float sum = 0.f;
#pragma unroll
  for (int i = 0; i < 3; i++) {
    int c = threadIdx.x + i * 256;
    v[i] = et[c] + ep[c];
    sum += v[i];
  }
  float mean = block_reduce_sum(sum, sbuf) * (1.f / DM);
  float vs = 0.f;
#pragma unroll
  for (int i = 0; i < 3; i++) { float d = v[i] - mean; vs += d * d; }
  float var = block_reduce_sum(vs, sbuf) * (1.f / DM);
  float inv = rsqrtf(var + 1e-5f);
#pragma unroll
  for (int i = 0; i < 3; i++) {
    int c = threadIdx.x + i * 256;
    x[(size_t)s * DM + c] = (v[i] - mean) * inv * gs[c] + gb[c];
  }
}

// ---------------- residual add + layernorm ----------------
__global__ __launch_bounds__(256) void add_ln_kernel(
    const float* __restrict__ xin, const float* __restrict__ t,
    const float* __restrict__ gs, const float* __restrict__ gb,
    float* __restrict__ xout) {
  __shared__ float sbuf[8];
  int s = blockIdx.x;
  const float* xr = xin + (size_t)s * DM;
  const float* tr = t + (size_t)s * DM;
  float v[3];
  float sum = 0.f;
#pragma unroll
  for (int i = 0; i < 3; i++) {
    int c = threadIdx.x + i * 256;
    v[i] = xr[c] + tr[c];
    sum += v[i];
  }
  float mean = block_reduce_sum(sum, sbuf) * (1.f / DM);
  float vs = 0.f;
#pragma unroll
  for (int i = 0; i < 3; i++) { float d = v[i] - mean; vs += d * d; }
  float var = block_reduce_sum(vs, sbuf) * (1.f / DM);
  float inv = rsqrtf(var + 1e-5f);
#pragma unroll
  for (int i = 0; i < 3; i++) {
    int c = threadIdx.x + i * 256;
    xout[(size_t)s * DM + c] = (v[i] - mean) * inv * gs[c] + gb[c];
  }
}

// ---------------- tiled fp32 GEMM:  C = alpha*(A@W + b), optional exact GELU ----------------
// A: [M,K] row-major, W: [K,N] row-major, C: [M,N]. M,N multiples of 64, K multiple of 16.
template <int ACT>
__global__ __launch_bounds__(256) void gemm_kernel(
    const float* __restrict__ A, const float* __restrict__ W,
    const float* __restrict__ bias, float* __restrict__ C,
    int N, int K, float alpha) {
  __shared__ float As[64][17];  // pad -> conflict-free broadcast reads
  __shared__ float Bs[16][64];
  int i0 = blockIdx.y * 64;
  int j0 = blockIdx.x * 64;
  int t = threadIdx.x;
  int tx = t & 15, ty = t >> 4;

  int ar = t >> 2;        // 0..63
  int ac = (t & 3) * 4;   // 0,4,8,12
  int br = t >> 4;        // 0..15
  int bc = (t & 15) * 4;  // 0..60

  float acc[4][4] = {};

  for (int k0 = 0; k0 < K; k0 += 16) {
    float4 av = *(const float4*)&A[(size_t)(i0 + ar) * K + k0 + ac];
    float4 bv = *(const float4*)&W[(size_t)(k0 + br) * N + j0 + bc];
    As[ar][ac + 0] = av.x; As[ar][ac + 1] = av.y;
    As[ar][ac + 2] = av.z; As[ar][ac + 3] = av.w;
    *(float4*)&Bs[br][bc] = bv;  // row stride 64 floats, 16B aligned
    __syncthreads();
#pragma unroll
    for (int kk = 0; kk < 16; kk++) {
      float a[4], b[4];
#pragma unroll
      for (int i = 0; i < 4; i++) a[i] = As[ty * 4 + i][kk];
#pragma unroll
      for (int j = 0; j < 4; j++) b[j] = Bs[kk][tx * 4 + j];
#pragma unroll
      for (int i = 0; i < 4; i++)
#pragma unroll
        for (int j = 0; j < 4; j++) acc[i][j] += a[i] * b[j];
    }
    __syncthreads();
  }

  float bj[4];
#pragma unroll
  for (int j = 0; j < 4; j++) bj[j] = bias[j0 + tx * 4 + j];
#pragma unroll
  for (int i = 0; i < 4; i++) {
#pragma unroll
    for (int j = 0; j < 4; j++) {
      float c = alpha * (acc[i][j] + bj[j]);
      if (ACT == 1) c = 0.5f * c * (1.0f + erff(c * 0.70710678118654752f));
      C[(size_t)(i0 + ty * 4 + i) * N + j0 + tx * 4 + j] = c;
    }
  }
}

// ---------------- sliding-window flash attention ----------------
// q,k,v,out: [S, DM] with head h at columns h*64..h*64+63. q pre-scaled.
// grid: (S/64, NH), block 256. Each block: 64 queries x one head.
__global__ __launch_bounds__(256) void attn_kernel(
    const float* __restrict__ q, const float* __restrict__ k,
    const float* __restrict__ v, float* __restrict__ out) {
  __shared__ float Qs[64][65], Ks[64][65], Vs[64][65], Ps[64][65];
  int h = blockIdx.y;
  int p0 = blockIdx.x * 64;
  int t = threadIdx.x, tx = t & 15, ty = t >> 4;

  {  // load Q tile
    int r = t >> 2;
    int cbase = (t & 3) * 4;
#pragma unroll
    for (int cc = 0; cc < 4; cc++) {
      int c = cbase + cc * 16;
      const float4 qv = *(const float4*)&q[(size_t)(p0 + r) * DM + h * HD + c];
      Qs[r][c + 0] = qv.x; Qs[r][c + 1] = qv.y;
      Qs[r][c + 2] = qv.z; Qs[r][c + 3] = qv.w;
    }
  }

  float O[4][4] = {};
  float m_[4], l_[4];
#pragma unroll
  for (int i = 0; i < 4; i++) { m_[i] = -1e30f; l_[i] = 0.f; }

  for (int blk = 0; blk < 17; blk++) {
    int kstart = p0 - WIN + blk * 64;
    __syncthreads();  // previous PV done (also covers Q-load on blk 0)
    {  // load K,V tiles (zero-fill out-of-sequence rows)
      int r = t >> 2;
      int cbase = (t & 3) * 4;
      int kp = kstart + r;
      bool okr = (kp >= 0) && (kp < S_LEN);
#pragma unroll
      for (int cc = 0; cc < 4; cc++) {
        int c = cbase + cc * 16;
        float4 kv = make_float4(0.f, 0.f, 0.f, 0.f);
        float4 vv = make_float4(0.f, 0.f, 0.f, 0.f);
        if (okr) {
          kv = *(const float4*)&k[(size_t)kp * DM + h * HD + c];
          vv = *(const float4*)&v[(size_t)kp * DM + h * HD + c];
        }
        Ks[r][c + 0] = kv.x; Ks[r][c + 1] = kv.y;
        Ks[r][c + 2] = kv.z; Ks[r][c + 3] = kv.w;
        Vs[r][c + 0] = vv.x; Vs[r][c + 1] = vv.y;
        Vs[r][c + 2] = vv.z; Vs[r][c + 3] = vv.w;
      }
    }
    __syncthreads();

    // scores: 4x4 microtile of Q@K^T
    float sc[4][4] = {};
#pragma unroll
    for (int d = 0; d < 64; d++) {
      float a[4], b[4];
#pragma unroll
      for (int i = 0; i < 4; i++) a[i] = Qs[ty * 4 + i][d];
#pragma unroll
      for (int j = 0; j < 4; j++) b[j] = Ks[tx * 4 + j][d];
#pragma unroll
      for (int i = 0; i < 4; i++)
#pragma unroll
        for (int j = 0; j < 4; j++) sc[i][j] += a[i] * b[j];
    }

    // band mask + online softmax (row spread over 16 lanes: tx)
#pragma unroll
    for (int i = 0; i < 4; i++) {
      int p = p0 + ty * 4 + i;
      bool val[4];
      float mx = -1e30f;
#pragma unroll
      for (int j = 0; j < 4; j++) {
        int kp2 = kstart + tx * 4 + j;
        int d = kp2 - p;
        val[j] = (kp2 >= 0) && (kp2 < S_LEN) && (d <= WIN) && (d >= -WIN);
        if (val[j]) mx = fmaxf(mx, sc[i][j]);
      }
#pragma unroll
      for (int dd = 1; dd < 16; dd <<= 1) mx = fmaxf(mx, __shfl_xor(mx, dd, 64));
      float newm = fmaxf(m_[i], mx);
      float fac = __expf(m_[i] - newm);  // both -1e30 -> 1, harmless (l=0,O=0)
      float rs = 0.f;
#pragma unroll
      for (int j = 0; j < 4; j++) {
        float pv = val[j] ? __expf(sc[i][j] - newm) : 0.f;
        Ps[ty * 4 + i][tx * 4 + j] = pv;
        rs += pv;
      }
#pragma unroll
      for (int dd = 1; dd < 16; dd <<= 1) rs += __shfl_xor(rs, dd, 64);
      l_[i] = l_[i] * fac + rs;
      m_[i] = newm;
#pragma unroll
      for (int j = 0; j < 4; j++) O[i][j] *= fac;
    }
    __syncthreads();  // Ps visible to whole block

    // O += P @ V
#pragma unroll
    for (int kk = 0; kk < 64; kk++) {
      float pp[4], vv[4];
#pragma unroll
      for (int i = 0; i < 4; i++) pp[i] = Ps[ty * 4 + i][kk];
#pragma unroll
      for (int j = 0; j < 4; j++) vv[j] = Vs[kk][tx * 4 + j];
#pragma unroll
      for (int i = 0; i < 4; i++)
#pragma unroll
        for (int j = 0; j < 4; j++) O[i][j] += pp[i] * vv[j];
    }
  }

#pragma unroll
  for (int i = 0; i < 4; i++) {
    float rinv = 1.f / l_[i];
#pragma unroll
    for (int j = 0; j < 4; j++) {
      out[(size_t)(p0 + ty * 4 + i) * DM + h * HD + tx * 4 + j] = O[i][j] * rinv;
    }
  }
}

// ---------------- launcher ----------------
extern "C" void kernel_launch(void* const* d_in, const int* in_sizes, int n_in,
                              void* d_out, int out_size, void* d_ws, size_t ws_size,
                              hipStream_t stream) {
  const int*   tokens  = (const int*)d_in[0];
  const float* emb_tok = (const float*)d_in[1];
  const float* emb_pos = (const float*)d_in[2];
  const float* ln_e_s  = (const float*)d_in[3];
  const float* ln_e_b  = (const float*)d_in[4];
  const float* Wq  = (const float*)d_in[5];
  const float* bq  = (const float*)d_in[6];
  const float* Wk  = (const float*)d_in[7];
  const float* bk  = (const float*)d_in[8];
  const float* Wv  = (const float*)d_in[9];
  const float* bv  = (const float*)d_in[10];
  const float* Wo  = (const float*)d_in[11];
  const float* bo  = (const float*)d_in[12];
  const float* ln1s = (const float*)d_in[13];
  const float* ln1b = (const float*)d_in[14];
  const float* W1f  = (const float*)d_in[15];
  const float* b1f  = (const float*)d_in[16];
  const float* W2f  = (const float*)d_in[17];
  const float* b2f  = (const float*)d_in[18];
  const float* ln2s = (const float*)d_in[19];
  const float* ln2b = (const float*)d_in[20];

  const size_t SD = (size_t)S_LEN * DM;  // 3,145,728 floats
  float* x  = (float*)d_ws;
  float* qb = x + SD;
  float* kb = qb + SD;
  float* vb = kb + SD;
  float* ab = vb + SD;
  float* tb = ab + SD;
  float* hb = qb;  // [S, DFF] = 4*SD floats, reuses q/k/v/a region (free by then)

  embed_ln_kernel<<<S_LEN, 256, 0, stream>>>(tokens, emb_tok, emb_pos, ln_e_s, ln_e_b, x);

  dim3 g768(DM / 64, S_LEN / 64);    // (12, 64)
  dim3 g3072(DFF / 64, S_LEN / 64);  // (48, 64)
  dim3 gatt(S_LEN / 64, NH);         // (64, 12)

  const float scale = 0.125f;  // 1/sqrt(64)

  for (int l = 0; l < NLAYER; l++) {
    const float* wq = Wq + (size_t)l * DM * DM;
    const float* wk = Wk + (size_t)l * DM * DM;
    const float* wv = Wv + (size_t)l * DM * DM;
    const float* wo = Wo + (size_t)l * DM * DM;
    const float* w1 = W1f + (size_t)l * DM * DFF;
    const float* w2 = W2f + (size_t)l * DFF * DM;

    gemm_kernel<0><<<g768, 256, 0, stream>>>(x, wq, bq + l * DM, qb, DM, DM, scale);
    gemm_kernel<0><<<g768, 256, 0, stream>>>(x, wk, bk + l * DM, kb, DM, DM, 1.f);
    gemm_kernel<0><<<g768, 256, 0, stream>>>(x, wv, bv + l * DM, vb, DM, DM, 1.f);
    attn_kernel<<<gatt, 256, 0, stream>>>(qb, kb, vb, ab);
    gemm_kernel<0><<<g768, 256, 0, stream>>>(ab, wo, bo + l * DM, tb, DM, DM, 1.f);
    add_ln_kernel<<<S_LEN, 256, 0, stream>>>(x, tb, ln1s + l * DM, ln1b + l * DM, x);
    gemm_kernel<1><<<g3072, 256, 0, stream>>>(x, w1, b1f + l * DFF, hb, DFF, DM, 1.f);
    gemm_kernel<0><<<g768, 256, 0, stream>>>(hb, w2, b2f + l * DM, tb, DM, DFF, 1.f);
    float* xout = (l == NLAYER - 1) ? (float*)d_out : x;
    add_ln_kernel<<<S_LEN, 256, 0, stream>>>(x, tb, ln2s + l * DM, ln2b + l * DM, xout);
  }
}

// Round 2
// 2208.893 us; speedup vs baseline: 3.3838x; 3.3838x over previous
//
#include <hip/hip_runtime.h>
#include <math.h>
#include <stdint.h>

typedef _Float16 f16;
typedef _Float16 f16x8 __attribute__((ext_vector_type(8)));
typedef _Float16 f16x4 __attribute__((ext_vector_type(4)));
typedef float f32x4 __attribute__((ext_vector_type(4)));

#define DM    768
#define SL    4096
#define NH    12
#define DFF   3072
#define NL    6
#define WIN   512
#define QKVN  2304

// ---------- async global->LDS 16B ----------
__device__ __forceinline__ void gl_lds16(const void* g, void* l) {
  __builtin_amdgcn_global_load_lds(
      (const __attribute__((address_space(1))) uint32_t*)(uintptr_t)g,
      (__attribute__((address_space(3))) uint32_t*)(uint32_t)(uintptr_t)l,
      16, 0, 0);
}

// stage a [128 rows][32 k] f16 tile (row-major, leading dim ld) into LDS,
// linear dest, source pre-swizzled so logical slot g lives at phys g^swz(row).
__device__ __forceinline__ void stage_tile(const f16* src, int ld, f16* lds, int tid) {
  int w = tid >> 6;
#pragma unroll
  for (int i = 0; i < 2; i++) {
    int c = i * 256 + tid;
    int row = c >> 2, sl = c & 3;
    int ssl = sl ^ (row & 3) ^ ((row >> 2) & 3);
    gl_lds16(src + (size_t)row * ld + ssl * 8, lds + (i * 256 + w * 64) * 8);
  }
}

// ---------------- block reduction helper ----------------
__device__ inline float block_reduce_sum(float v, float* sbuf) {
#pragma unroll
  for (int off = 32; off > 0; off >>= 1) v += __shfl_down(v, off, 64);
  int lane = threadIdx.x & 63;
  int wid  = threadIdx.x >> 6;
  if (lane == 0) sbuf[wid] = v;
  __syncthreads();
  if (threadIdx.x == 0) {
    float r = 0.f;
    for (int i = 0; i < 4; i++) r += sbuf[i];
    sbuf[0] = r;
  }
  __syncthreads();
  float r = sbuf[0];
  __syncthreads();
  return r;
}

// ---------------- embedding + layernorm (fp32 + f16 copy) ----------------
__global__ __launch_bounds__(256) void embed_ln_kernel(
    const int* __restrict__ tokens, const float* __restrict__ emb_tok,
    const float* __restrict__ emb_pos, const float* __restrict__ gs,
    const float* __restrict__ gb, float* __restrict__ x, f16* __restrict__ xh) {
  __shared__ float sbuf[8];
  int s = blockIdx.x;
  int tok = tokens[s];
  const float* et = emb_tok + (size_t)tok * DM;
  const float* ep = emb_pos + (size_t)s * DM;
  float v[3];
  float sum = 0.f;
#pragma unroll
  for (int i = 0; i < 3; i++) {
    int c = threadIdx.x + i * 256;
    v[i] = et[c] + ep[c];
    sum += v[i];
  }
  float mean = block_reduce_sum(sum, sbuf) * (1.f / DM);
  float vs = 0.f;
#pragma unroll
  for (int i = 0; i < 3; i++) { float d = v[i] - mean; vs += d * d; }
  float var = block_reduce_sum(vs, sbuf) * (1.f / DM);
  float inv = rsqrtf(var + 1e-5f);
#pragma unroll
  for (int i = 0; i < 3; i++) {
    int c = threadIdx.x + i * 256;
    float o = (v[i] - mean) * inv * gs[c] + gb[c];
    x[(size_t)s * DM + c] = o;
    xh[(size_t)s * DM + c] = (f16)o;
  }
}

// ---------------- residual add + layernorm (fp32 + f16 copy) ----------------
__global__ __launch_bounds__(256) void add_ln_kernel(
    const float* __restrict__ xin, const float* __restrict__ t,
    const float* __restrict__ gs, const float* __restrict__ gb,
    float* __restrict__ xout, f16* __restrict__ xh) {
  __shared__ float sbuf[8];
  int s = blockIdx.x;
  const float* xr = xin + (size_t)s * DM;
  const float* tr = t + (size_t)s * DM;
  float v[3];
  float sum = 0.f;
#pragma unroll
  for (int i = 0; i < 3; i++) {
    int c = threadIdx.x + i * 256;
    v[i] = xr[c] + tr[c];
    sum += v[i];
  }
  float mean = block_reduce_sum(sum, sbuf) * (1.f / DM);
  float vs = 0.f;
#pragma unroll
  for (int i = 0; i < 3; i++) { float d = v[i] - mean; vs += d * d; }
  float var = block_reduce_sum(vs, sbuf) * (1.f / DM);
  float inv = rsqrtf(var + 1e-5f);
#pragma unroll
  for (int i = 0; i < 3; i++) {
    int c = threadIdx.x + i * 256;
    float o = (v[i] - mean) * inv * gs[c] + gb[c];
    xout[(size_t)s * DM + c] = o;
    xh[(size_t)s * DM + c] = (f16)o;
  }
}

// ---------------- weight transpose + f16 convert: src fp32 [R][C] -> dst f16 [C][R] ----
__global__ __launch_bounds__(256) void wtrans_kernel(
    const float* __restrict__ src, f16* __restrict__ dst, int R, int C, float scale) {
  __shared__ float t[32][33];
  int c0 = blockIdx.x * 32, r0 = blockIdx.y * 32;
  int tid = threadIdx.x;
  int row = tid >> 3, c4 = (tid & 7) * 4;
  float4 v4 = *(const float4*)(src + (size_t)(r0 + row) * C + c0 + c4);
  t[row][c4 + 0] = v4.x; t[row][c4 + 1] = v4.y;
  t[row][c4 + 2] = v4.z; t[row][c4 + 3] = v4.w;
  __syncthreads();
  int cc = tid >> 3, r4 = (tid & 7) * 4;
  f16x4 o4;
#pragma unroll
  for (int i = 0; i < 4; i++) o4[i] = (f16)(t[r4 + i][cc] * scale);
  *(f16x4*)(dst + (size_t)(c0 + cc) * R + r0 + r4) = o4;
}

// ---------------- V transpose: qkv f16 [SL][QKVN] (V at col 1536+) -> vT [768][SL] ----
__global__ __launch_bounds__(256) void vtrans_kernel(
    const f16* __restrict__ qkv, f16* __restrict__ vT) {
  __shared__ f16 t[32][33];
  int c0 = blockIdx.x * 32;  // d index within 768
  int s0 = blockIdx.y * 32;
  int tid = threadIdx.x;
  int row = tid >> 3, c4 = (tid & 7) * 4;
  f16x4 v4 = *(const f16x4*)(qkv + (size_t)(s0 + row) * QKVN + 1536 + c0 + c4);
#pragma unroll
  for (int i = 0; i < 4; i++) t[row][c4 + i] = v4[i];
  __syncthreads();
  int cc = tid >> 3, r4 = (tid & 7) * 4;
  f16x4 o4;
#pragma unroll
  for (int i = 0; i < 4; i++) o4[i] = t[r4 + i][cc];
  *(f16x4*)(vT + (size_t)(c0 + cc) * SL + s0 + r4) = o4;
}

// ---------------- fused bias for qkv (q pre-scaled) ----------------
__global__ void bias_fuse_kernel(const float* __restrict__ bq, const float* __restrict__ bk,
                                 const float* __restrict__ bv, float* __restrict__ bqkv) {
  int i = blockIdx.x * 256 + threadIdx.x;
  if (i >= NL * QKVN) return;
  int lay = i / QKVN, c = i % QKVN;
  float v;
  if (c < DM) v = bq[lay * DM + c] * 0.125f;
  else if (c < 2 * DM) v = bk[lay * DM + c - DM];
  else v = bv[lay * DM + c - 2 * DM];
  bqkv[i] = v;
}

// ---------------- f16 MFMA GEMM: C = A@Wt^T + bias (Wt is [N][K]) ----------------
// BM=BN=128, BK=32, 256 thr = 4 waves, wave = 64x64 (4x4 frags of 16x16x32).
// ACT: 0=none 1=exact gelu. OH: 0 -> fp32 out Cf, 1 -> f16 out Ch.
template <int ACT, int OH>
__global__ __launch_bounds__(256) void gemm_f16(
    const f16* __restrict__ A, const f16* __restrict__ Wt,
    const float* __restrict__ bias, float* __restrict__ Cf,
    f16* __restrict__ Ch, int N, int K) {
  __shared__ f16 As[128 * 32];
  __shared__ f16 Bs[128 * 32];
  int tid = threadIdx.x;
  int l = tid & 63, lr = l & 15, lg = l >> 4;
  int w = tid >> 6, wm = (w >> 1) * 64, wn = (w & 1) * 64;
  size_t i0 = (size_t)blockIdx.y * 128, j0 = (size_t)blockIdx.x * 128;
  f32x4 acc[4][4] = {};
  const f16* Ab = A + i0 * K;
  const f16* Bb = Wt + j0 * K;
  for (int k0 = 0; k0 < K; k0 += 32) {
    stage_tile(Ab + k0, K, As, tid);
    stage_tile(Bb + k0, K, Bs, tid);
    __syncthreads();
    f16x8 af[4], bf[4];
#pragma unroll
    for (int mi = 0; mi < 4; mi++) {
      int row = wm + mi * 16 + lr;
      int ph = lg ^ (row & 3) ^ ((row >> 2) & 3);
      af[mi] = *(const f16x8*)((const char*)As + row * 64 + ph * 16);
    }
#pragma unroll
    for (int ni = 0; ni < 4; ni++) {
      int row = wn + ni * 16 + lr;
      int ph = lg ^ (row & 3) ^ ((row >> 2) & 3);
      bf[ni] = *(const f16x8*)((const char*)Bs + row * 64 + ph * 16);
    }
#pragma unroll
    for (int mi = 0; mi < 4; mi++)
#pragma unroll
      for (int ni = 0; ni < 4; ni++)
        acc[mi][ni] = __builtin_amdgcn_mfma_f32_16x16x32_f16(af[mi], bf[ni], acc[mi][ni], 0, 0, 0);
    __syncthreads();
  }
#pragma unroll
  for (int ni = 0; ni < 4; ni++) {
    int col = (int)j0 + wn + ni * 16 + lr;
    float bc = bias[col];
#pragma unroll
    for (int mi = 0; mi < 4; mi++) {
#pragma unroll
      for (int r = 0; r < 4; r++) {
        size_t rowg = i0 + wm + mi * 16 + lg * 4 + r;
        float v2 = acc[mi][ni][r] + bc;
        if (ACT == 1) v2 = 0.5f * v2 * (1.f + erff(v2 * 0.70710678118654752440f));
        if (OH == 0) Cf[rowg * N + col] = v2;
        else         Ch[rowg * N + col] = (f16)v2;
      }
    }
  }
}

// ---------------- sliding-window flash attention, f16 MFMA ----------------
// qkv: [SL][2304] f16 (q pre-scaled; k at +768, v unused here), vT: [768][SL] f16.
// grid (SL/64, NH), 256 thr = 4 waves; wave handles 16 queries.
__global__ __launch_bounds__(256) void attn_f16(
    const f16* __restrict__ qkv, const f16* __restrict__ vT, f16* __restrict__ ab) {
  __shared__ f16 Plds[4][1024];  // per-wave 16x64 P tile, XOR-swizzled
  int h = blockIdx.y;
  int p0 = blockIdx.x * 64;
  int tid = threadIdx.x;
  int w = tid >> 6, l = tid & 63, lr = l & 15, lg = l >> 4;
  int qbase = p0 + w * 16;
  char* pb = (char*)&Plds[w][0];

  f16x8 aq[2];
#pragma unroll
  for (int c = 0; c < 2; c++)
    aq[c] = *(const f16x8*)(qkv + (size_t)(qbase + lr) * QKVN + h * 64 + c * 32 + lg * 8);

  f32x4 o[4] = {};
  float m_[4], l_[4];
#pragma unroll
  for (int r = 0; r < 4; r++) { m_[r] = -1e30f; l_[r] = 0.f; }

  for (int kb = 0; kb < 17; kb++) {
    int kstart = p0 - WIN + kb * 64;
    f32x4 s[4] = {};
#pragma unroll
    for (int nt = 0; nt < 4; nt++) {
      int kpos = kstart + nt * 16 + lr;
      bool okk = (unsigned)kpos < SL;
#pragma unroll
      for (int c = 0; c < 2; c++) {
        f16x8 kf = {};
        if (okk) kf = *(const f16x8*)(qkv + (size_t)kpos * QKVN + DM + h * 64 + c * 32 + lg * 8);
        s[nt] = __builtin_amdgcn_mfma_f32_16x16x32_f16(aq[c], kf, s[nt], 0, 0, 0);
      }
    }
    // mask + online softmax; lane's rows are lg*4+r, col is lr within 16-tile nt
    float mx[4] = {-1e30f, -1e30f, -1e30f, -1e30f};
#pragma unroll
    for (int nt = 0; nt < 4; nt++) {
      int kpos = kstart + nt * 16 + lr;
#pragma unroll
      for (int r = 0; r < 4; r++) {
        int q = qbase + lg * 4 + r;
        int d = kpos - q;
        bool valid = ((unsigned)kpos < SL) && (d <= WIN) && (d >= -WIN);
        float sv = valid ? s[nt][r] : -1e30f;
        s[nt][r] = sv;
        mx[r] = fmaxf(mx[r], sv);
      }
    }
#pragma unroll
    for (int r = 0; r < 4; r++)
#pragma unroll
      for (int d = 1; d < 16; d <<= 1) mx[r] = fmaxf(mx[r], __shfl_xor(mx[r], d));
    float fac[4], rs[4];
#pragma unroll
    for (int r = 0; r < 4; r++) {
      float nm = fmaxf(m_[r], mx[r]);
      fac[r] = __expf(m_[r] - nm);
      m_[r] = nm;
      rs[r] = 0.f;
    }
#pragma unroll
    for (int nt = 0; nt < 4; nt++) {
#pragma unroll
      for (int r = 0; r < 4; r++) {
        float sv = s[nt][r];
        float p = (sv > -1e29f) ? __expf(sv - m_[r]) : 0.f;
        rs[r] += p;
        int q = lg * 4 + r;
        int bo2 = q * 128 + (((nt * 16 + lr) * 2) ^ ((q & 7) << 4));
        *(f16*)(pb + bo2) = (f16)p;
      }
    }
#pragma unroll
    for (int r = 0; r < 4; r++) {
#pragma unroll
      for (int d = 1; d < 16; d <<= 1) rs[r] += __shfl_xor(rs[r], d);
      l_[r] = l_[r] * fac[r] + rs[r];
    }
#pragma unroll
    for (int dt = 0; dt < 4; dt++)
#pragma unroll
      for (int r = 0; r < 4; r++) o[dt][r] *= fac[r];
    // O += P @ V
#pragma unroll
    for (int c = 0; c < 2; c++) {
      f16x8 pa = *(const f16x8*)(pb + lr * 128 + ((c * 64 + lg * 16) ^ ((lr & 7) << 4)));
      int pos0 = kstart + c * 32 + lg * 8;
      bool okv = (unsigned)pos0 < SL;
#pragma unroll
      for (int dt = 0; dt < 4; dt++) {
        f16x8 vf = {};
        if (okv) vf = *(const f16x8*)(vT + (size_t)(h * 64 + dt * 16 + lr) * SL + pos0);
        o[dt] = __builtin_amdgcn_mfma_f32_16x16x32_f16(pa, vf, o[dt], 0, 0, 0);
      }
    }
  }
  float rinv[4];
#pragma unroll
  for (int r = 0; r < 4; r++) rinv[r] = 1.f / l_[r];
#pragma unroll
  for (int dt = 0; dt < 4; dt++)
#pragma unroll
    for (int r = 0; r < 4; r++)
      ab[(size_t)(qbase + lg * 4 + r) * DM + h * 64 + dt * 16 + lr] = (f16)(o[dt][r] * rinv[r]);
}

// ---------------- launcher ----------------
extern "C" void kernel_launch(void* const* d_in, const int* in_sizes, int n_in,
                              void* d_out, int out_size, void* d_ws, size_t ws_size,
                              hipStream_t stream) {
  const int*   tokens  = (const int*)d_in[0];
  const float* emb_tok = (const float*)d_in[1];
  const float* emb_pos = (const float*)d_in[2];
  const float* ln_e_s  = (const float*)d_in[3];
  const float* ln_e_b  = (const float*)d_in[4];
  const float* Wq  = (const float*)d_in[5];
  const float* bq  = (const float*)d_in[6];
  const float* Wk  = (const float*)d_in[7];
  const float* bk  = (const float*)d_in[8];
  const float* Wv  = (const float*)d_in[9];
  const float* bv  = (const float*)d_in[10];
  const float* Wo  = (const float*)d_in[11];
  const float* bo  = (const float*)d_in[12];
  const float* ln1s = (const float*)d_in[13];
  const float* ln1b = (const float*)d_in[14];
  const float* W1f  = (const float*)d_in[15];
  const float* b1f  = (const float*)d_in[16];
  const float* W2f  = (const float*)d_in[17];
  const float* b2f  = (const float*)d_in[18];
  const float* ln2s = (const float*)d_in[19];
  const float* ln2b = (const float*)d_in[20];

  char* wsb = (char*)d_ws;
  float* x    = (float*)(wsb + 0);           // 12,582,912 B
  float* tb   = (float*)(wsb + 12582912);    // 12,582,912 B
  f16*   xh   = (f16*)  (wsb + 25165824);    //  6,291,456 B
  char*  Ar   = wsb + 31457280;              // 31,457,280 B activation region
  f16*   qkv  = (f16*)(Ar);                  // 18,874,368 B
  f16*   vT   = (f16*)(Ar + 18874368);       //  6,291,456 B
  f16*   abf  = (f16*)(Ar + 25165824);       //  6,291,456 B
  f16*   hbuf = (f16*)(Ar);                  // 25,165,824 B (reuses qkv+vT)
  f16*   Wbuf = (f16*)(wsb + 62914560);      //  4,718,592 B weight scratch
  float* bqkv = (float*)(wsb + 67633152);    //     55,296 B

  bias_fuse_kernel<<<(NL * QKVN + 255) / 256, 256, 0, stream>>>(bq, bk, bv, bqkv);
  embed_ln_kernel<<<SL, 256, 0, stream>>>(tokens, emb_tok, emb_pos, ln_e_s, ln_e_b, x, xh);

  dim3 t24(24, 24), tW1(96, 24), tW2(24, 96);
  dim3 gqkv(QKVN / 128, SL / 128);  // (18,32)
  dim3 g768(DM / 128, SL / 128);    // (6,32)
  dim3 gffn(DFF / 128, SL / 128);   // (24,32)
  dim3 gvt(DM / 32, SL / 32);       // (24,128)
  dim3 gatt(SL / 64, NH);           // (64,12)

  for (int lay = 0; lay < NL; lay++) {
    wtrans_kernel<<<t24, 256, 0, stream>>>(Wq + (size_t)lay * DM * DM, Wbuf, DM, DM, 0.125f);
    wtrans_kernel<<<t24, 256, 0, stream>>>(Wk + (size_t)lay * DM * DM, Wbuf + DM * DM, DM, DM, 1.f);
    wtrans_kernel<<<t24, 256, 0, stream>>>(Wv + (size_t)lay * DM * DM, Wbuf + 2 * DM * DM, DM, DM, 1.f);
    gemm_f16<0, 1><<<gqkv, 256, 0, stream>>>(xh, Wbuf, bqkv + lay * QKVN, nullptr, qkv, QKVN, DM);
    vtrans_kernel<<<gvt, 256, 0, stream>>>(qkv, vT);
    attn_f16<<<gatt, 256, 0, stream>>>(qkv, vT, abf);
    wtrans_kernel<<<t24, 256, 0, stream>>>(Wo + (size_t)lay * DM * DM, Wbuf, DM, DM, 1.f);
    gemm_f16<0, 0><<<g768, 256, 0, stream>>>(abf, Wbuf, bo + lay * DM, tb, nullptr, DM, DM);
    add_ln_kernel<<<SL, 256, 0, stream>>>(x, tb, ln1s + lay * DM, ln1b + lay * DM, x, xh);
    wtrans_kernel<<<tW1, 256, 0, stream>>>(W1f + (size_t)lay * DM * DFF, Wbuf, DM, DFF, 1.f);
    gemm_f16<1, 1><<<gffn, 256, 0, stream>>>(xh, Wbuf, b1f + lay * DFF, nullptr, hbuf, DFF, DM);
    wtrans_kernel<<<tW2, 256, 0, stream>>>(W2f + (size_t)lay * DFF * DM, Wbuf, DFF, DM, 1.f);
    gemm_f16<0, 0><<<g768, 256, 0, stream>>>(hbuf, Wbuf, b2f + lay * DM, tb, nullptr, DM, DFF);
    float* xo = (lay == NL - 1) ? (float*)d_out : x;
    add_ln_kernel<<<SL, 256, 0, stream>>>(x, tb, ln2s + lay * DM, ln2b + lay * DM, xo, xh);
  }
}

// Round 5
// 1640.760 us; speedup vs baseline: 4.5555x; 1.3463x over previous
//
#include <hip/hip_runtime.h>
#include <math.h>
#include <stdint.h>

typedef _Float16 f16;
typedef _Float16 f16x8 __attribute__((ext_vector_type(8)));
typedef _Float16 f16x4 __attribute__((ext_vector_type(4)));
typedef float f32x4 __attribute__((ext_vector_type(4)));

#define DM    768
#define SL    4096
#define NH    12
#define DFF   3072
#define NL    6
#define WIN   512
#define QKVN  2304
#define HSZ   (SL * 64)  // per-head elements

// ---------- async global->LDS 16B ----------
__device__ __forceinline__ void gl_lds16(const void* g, void* l) {
  __builtin_amdgcn_global_load_lds(
      (const __attribute__((address_space(1))) uint32_t*)(uintptr_t)g,
      (__attribute__((address_space(3))) uint32_t*)(uint32_t)(uintptr_t)l,
      16, 0, 0);
}

// stage a [ROWS rows][32 k] f16 tile (row-major, leading dim ld) into LDS,
// linear dest, source pre-swizzled (4 slots/row, XOR by row bits).
template <int ROWS>
__device__ __forceinline__ void stage_tile(const f16* src, int ld, f16* lds, int tid) {
  int w = tid >> 6;
#pragma unroll
  for (int i = 0; i < ROWS / 64; i++) {
    int c = i * 256 + tid;
    int row = c >> 2, sl = c & 3;
    int ssl = sl ^ (row & 3) ^ ((row >> 2) & 3);
    gl_lds16(src + (size_t)row * ld + ssl * 8, lds + (size_t)(i * 256 + w * 64) * 8);
  }
}

// stage K tile [64 kpos][64 d] and V^T tile [64 d][64 kpos] (8 slots/row, XOR row&7).
__device__ __forceinline__ void stage_kv(const f16* Kb, const f16* Vb, int kstart,
                                         f16* ks, f16* vs, int tid) {
  int w = tid >> 6;
#pragma unroll
  for (int p = 0; p < 2; p++) {
    int g = p * 256 + tid;
    int row = g >> 3, psl = g & 7;
    int sl = psl ^ (row & 7);
    int gr = kstart + row;
    gr = gr < 0 ? 0 : (gr > SL - 1 ? SL - 1 : gr);  // clamp; masked later
    gl_lds16(Kb + (size_t)gr * 64 + sl * 8, ks + (size_t)(p * 256 + w * 64) * 8);
    int col = kstart + sl * 8;
    col = col < 0 ? 0 : (col > SL - 8 ? SL - 8 : col);
    gl_lds16(Vb + (size_t)row * SL + col, vs + (size_t)(p * 256 + w * 64) * 8);
  }
}

// ---------------- block reduction helper ----------------
__device__ inline float block_reduce_sum(float v, float* sbuf) {
#pragma unroll
  for (int off = 32; off > 0; off >>= 1) v += __shfl_down(v, off, 64);
  int lane = threadIdx.x & 63;
  int wid  = threadIdx.x >> 6;
  if (lane == 0) sbuf[wid] = v;
  __syncthreads();
  if (threadIdx.x == 0) {
    float r = 0.f;
    for (int i = 0; i < 4; i++) r += sbuf[i];
    sbuf[0] = r;
  }
  __syncthreads();
  float r = sbuf[0];
  __syncthreads();
  return r;
}

// ---------------- embedding + layernorm (fp32 + f16 copy) ----------------
__global__ __launch_bounds__(256) void embed_ln_kernel(
    const int* __restrict__ tokens, const float* __restrict__ emb_tok,
    const float* __restrict__ emb_pos, const float* __restrict__ gs,
    const float* __restrict__ gb, float* __restrict__ x, f16* __restrict__ xh) {
  __shared__ float sbuf[8];
  int s = blockIdx.x;
  int tok = tokens[s];
  const float* et = emb_tok + (size_t)tok * DM;
  const float* ep = emb_pos + (size_t)s * DM;
  float v[3];
  float sum = 0.f;
#pragma unroll
  for (int i = 0; i < 3; i++) {
    int c = threadIdx.x + i * 256;
    v[i] = et[c] + ep[c];
    sum += v[i];
  }
  float mean = block_reduce_sum(sum, sbuf) * (1.f / DM);
  float vs = 0.f;
#pragma unroll
  for (int i = 0; i < 3; i++) { float d = v[i] - mean; vs += d * d; }
  float var = block_reduce_sum(vs, sbuf) * (1.f / DM);
  float inv = rsqrtf(var + 1e-5f);
#pragma unroll
  for (int i = 0; i < 3; i++) {
    int c = threadIdx.x + i * 256;
    float o = (v[i] - mean) * inv * gs[c] + gb[c];
    x[(size_t)s * DM + c] = o;
    xh[(size_t)s * DM + c] = (f16)o;
  }
}

// ---------------- residual add + layernorm (fp32 + f16 copy) ----------------
__global__ __launch_bounds__(256) void add_ln_kernel(
    const float* __restrict__ xin, const float* __restrict__ t,
    const float* __restrict__ gs, const float* __restrict__ gb,
    float* __restrict__ xout, f16* __restrict__ xh) {
  __shared__ float sbuf[8];
  int s = blockIdx.x;
  const float* xr = xin + (size_t)s * DM;
  const float* tr = t + (size_t)s * DM;
  float v[3];
  float sum = 0.f;
#pragma unroll
  for (int i = 0; i < 3; i++) {
    int c = threadIdx.x + i * 256;
    v[i] = xr[c] + tr[c];
    sum += v[i];
  }
  float mean = block_reduce_sum(sum, sbuf) * (1.f / DM);
  float vs = 0.f;
#pragma unroll
  for (int i = 0; i < 3; i++) { float d = v[i] - mean; vs += d * d; }
  float var = block_reduce_sum(vs, sbuf) * (1.f / DM);
  float inv = rsqrtf(var + 1e-5f);
#pragma unroll
  for (int i = 0; i < 3; i++) {
    int c = threadIdx.x + i * 256;
    float o = (v[i] - mean) * inv * gs[c] + gb[c];
    xout[(size_t)s * DM + c] = o;
    xh[(size_t)s * DM + c] = (f16)o;
  }
}

// ---------------- weight transpose + f16 convert: src fp32 [R][C] -> dst f16 [C][R] ----
__global__ __launch_bounds__(256) void wtrans_kernel(
    const float* __restrict__ src, f16* __restrict__ dst, int R, int C, float scale) {
  __shared__ float t[32][33];
  int c0 = blockIdx.x * 32, r0 = blockIdx.y * 32;
  int tid = threadIdx.x;
  int row = tid >> 3, c4 = (tid & 7) * 4;
  float4 v4 = *(const float4*)(src + (size_t)(r0 + row) * C + c0 + c4);
  t[row][c4 + 0] = v4.x; t[row][c4 + 1] = v4.y;
  t[row][c4 + 2] = v4.z; t[row][c4 + 3] = v4.w;
  __syncthreads();
  int cc = tid >> 3, r4 = (tid & 7) * 4;
  f16x4 o4;
#pragma unroll
  for (int i = 0; i < 4; i++) o4[i] = (f16)(t[r4 + i][cc] * scale);
  *(f16x4*)(dst + (size_t)(c0 + cc) * R + r0 + r4) = o4;
}

// fused QKV weight transpose (z selects q/k/v; q gets 1/8 scale folded in)
__global__ __launch_bounds__(256) void wtrans3_kernel(
    const float* __restrict__ Wq, const float* __restrict__ Wk,
    const float* __restrict__ Wv, f16* __restrict__ dst, int lay) {
  __shared__ float t[32][33];
  int z = blockIdx.z;
  const float* src = (z == 0 ? Wq : (z == 1 ? Wk : Wv)) + (size_t)lay * DM * DM;
  float scale = (z == 0) ? 0.125f : 1.f;
  f16* d = dst + (size_t)z * DM * DM;
  int c0 = blockIdx.x * 32, r0 = blockIdx.y * 32;
  int tid = threadIdx.x;
  int row = tid >> 3, c4 = (tid & 7) * 4;
  float4 v4 = *(const float4*)(src + (size_t)(r0 + row) * DM + c0 + c4);
  t[row][c4 + 0] = v4.x; t[row][c4 + 1] = v4.y;
  t[row][c4 + 2] = v4.z; t[row][c4 + 3] = v4.w;
  __syncthreads();
  int cc = tid >> 3, r4 = (tid & 7) * 4;
  f16x4 o4;
#pragma unroll
  for (int i = 0; i < 4; i++) o4[i] = (f16)(t[r4 + i][cc] * scale);
  *(f16x4*)(d + (size_t)(c0 + cc) * DM + r0 + r4) = o4;
}

// ---------------- per-head V transpose: vh [NH][SL][64] -> vTh [NH][64][SL] ----
__global__ __launch_bounds__(256) void vtrans_kernel(
    const f16* __restrict__ vh, f16* __restrict__ vTh) {
  __shared__ f16 t[32][33];
  int h = blockIdx.z;
  int d0 = blockIdx.x * 32, s0 = blockIdx.y * 32;
  int tid = threadIdx.x;
  int row = tid >> 3, c4 = (tid & 7) * 4;
  f16x4 v4 = *(const f16x4*)(vh + ((size_t)h * SL + s0 + row) * 64 + d0 + c4);
#pragma unroll
  for (int i = 0; i < 4; i++) t[row][c4 + i] = v4[i];
  __syncthreads();
  int cc = tid >> 3, r4 = (tid & 7) * 4;
  f16x4 o4;
#pragma unroll
  for (int i = 0; i < 4; i++) o4[i] = t[r4 + i][cc];
  *(f16x4*)(vTh + ((size_t)h * 64 + d0 + cc) * SL + s0 + r4) = o4;
}

// ---------------- fused bias for qkv (q pre-scaled) ----------------
__global__ void bias_fuse_kernel(const float* __restrict__ bq, const float* __restrict__ bk,
                                 const float* __restrict__ bv, float* __restrict__ bqkv) {
  int i = blockIdx.x * 256 + threadIdx.x;
  if (i >= NL * QKVN) return;
  int lay = i / QKVN, c = i % QKVN;
  float v;
  if (c < DM) v = bq[lay * DM + c] * 0.125f;
  else if (c < 2 * DM) v = bk[lay * DM + c - DM];
  else v = bv[lay * DM + c - 2 * DM];
  bqkv[i] = v;
}

// ---------------- f16 MFMA GEMM: C = A@Wt^T + bias (Wt is [N][K]) ----------------
// BM=128, BN=NF*32, BK=32, 256 thr = 4 waves (2m x 2n), double-buffered LDS,
// one barrier per K-step (stage t+1 overlaps compute t).
// ACT: 0=none 1=exact gelu. OH: 0 fp32 Cf, 1 f16 Ch row-major, 2 qkv head-split.
template <int ACT, int OH, int NF>
__global__ __launch_bounds__(256) void gemm_f16(
    const f16* __restrict__ A, const f16* __restrict__ Wt,
    const float* __restrict__ bias, float* __restrict__ Cf,
    f16* __restrict__ Ch, int N, int K) {
  __shared__ f16 As[2][128 * 32];
  __shared__ f16 Bs[2][NF * 32 * 32];
  int tid = threadIdx.x;
  int l = tid & 63, lr = l & 15, lg = l >> 4;
  int w = tid >> 6, wm = (w >> 1) * 64, wn = (w & 1) * (NF * 16);
  size_t i0 = (size_t)blockIdx.y * 128, j0 = (size_t)blockIdx.x * (NF * 32);
  f32x4 acc[4][NF] = {};
  const f16* Ab = A + i0 * K;
  const f16* Bb = Wt + j0 * K;
  stage_tile<128>(Ab, K, As[0], tid);
  stage_tile<NF * 32>(Bb, K, Bs[0], tid);
  for (int k0 = 0; k0 < K; k0 += 32) {
    int cur = (k0 >> 5) & 1;
    __syncthreads();  // vmcnt drain: tile k0 staged & visible
    if (k0 + 32 < K) {
      stage_tile<128>(Ab + k0 + 32, K, As[cur ^ 1], tid);
      stage_tile<NF * 32>(Bb + k0 + 32, K, Bs[cur ^ 1], tid);
    }
    f16x8 af[4], bf[NF];
#pragma unroll
    for (int mi = 0; mi < 4; mi++) {
      int row = wm + mi * 16 + lr;
      int ph = lg ^ (row & 3) ^ ((row >> 2) & 3);
      af[mi] = *(const f16x8*)((const char*)As[cur] + row * 64 + ph * 16);
    }
#pragma unroll
    for (int ni = 0; ni < NF; ni++) {
      int row = wn + ni * 16 + lr;
      int ph = lg ^ (row & 3) ^ ((row >> 2) & 3);
      bf[ni] = *(const f16x8*)((const char*)Bs[cur] + row * 64 + ph * 16);
    }
#pragma unroll
    for (int mi = 0; mi < 4; mi++)
#pragma unroll
      for (int ni = 0; ni < NF; ni++)
        acc[mi][ni] = __builtin_amdgcn_mfma_f32_16x16x32_f16(af[mi], bf[ni], acc[mi][ni], 0, 0, 0);
  }
#pragma unroll
  for (int ni = 0; ni < NF; ni++) {
    int col = (int)j0 + wn + ni * 16 + lr;
    float bc = bias[col];
#pragma unroll
    for (int mi = 0; mi < 4; mi++) {
#pragma unroll
      for (int r = 0; r < 4; r++) {
        size_t rowg = i0 + wm + mi * 16 + lg * 4 + r;
        float v2 = acc[mi][ni][r] + bc;
        if (ACT == 1) v2 = 0.5f * v2 * (1.f + erff(v2 * 0.70710678118654752440f));
        if (OH == 0) Cf[rowg * N + col] = v2;
        else if (OH == 1) Ch[rowg * N + col] = (f16)v2;
        else {  // qkv head-split: [3*NH][SL][64]
          Ch[((size_t)(col >> 6) * SL + rowg) * 64 + (col & 63)] = (f16)v2;
        }
      }
    }
  }
}

// ---------------- sliding-window flash attention, f16 MFMA, LDS-staged K/V ----------------
// qh,kh: [NH][SL][64] (q pre-scaled), vTh: [NH][64][SL]. grid 768 blocks, 256 thr.
__global__ __launch_bounds__(256) void attn_f16(
    const f16* __restrict__ qh, const f16* __restrict__ kh,
    const f16* __restrict__ vTh, f16* __restrict__ ab) {
  __shared__ f16 Ks[2][64 * 64];
  __shared__ f16 Vs[2][64 * 64];
  __shared__ f16 Plds[4][1024];
  int bid = blockIdx.x;
  int wid = (bid & 7) * 96 + (bid >> 3);  // XCD-contiguous work chunks
  int h = wid >> 6;
  int p0 = (wid & 63) << 6;
  int tid = threadIdx.x;
  int w = tid >> 6, l = tid & 63, lr = l & 15, lg = l >> 4;
  int qbase = p0 + w * 16;
  char* pb = (char*)&Plds[w][0];
  const f16* Kb = kh + (size_t)h * HSZ;
  const f16* Vb = vTh + (size_t)h * HSZ;

  f16x8 aq[2];
#pragma unroll
  for (int c = 0; c < 2; c++)
    aq[c] = *(const f16x8*)(qh + (size_t)h * HSZ + (size_t)(qbase + lr) * 64 + c * 32 + lg * 8);

  f32x4 o[4] = {};
  float m_[4], l_[4];
#pragma unroll
  for (int r = 0; r < 4; r++) { m_[r] = -1e30f; l_[r] = 0.f; }

  int kb0 = (WIN - p0) > 0 ? ((WIN - p0) >> 6) : 0;
  int kb1 = (SL + WIN - p0 - 1) >> 6; if (kb1 > 16) kb1 = 16;

  stage_kv(Kb, Vb, p0 - WIN + kb0 * 64, Ks[0], Vs[0], tid);

  for (int kb = kb0; kb <= kb1; kb++) {
    int cur = (kb - kb0) & 1;
    int kstart = p0 - WIN + kb * 64;
    __syncthreads();  // vmcnt drain -> tile kb staged; all waves done with buf[cur^1]
    if (kb < kb1)
      stage_kv(Kb, Vb, kstart + 64, Ks[cur ^ 1], Vs[cur ^ 1], tid);  // overlaps compute

    const char* kbuf = (const char*)&Ks[cur][0];
    f32x4 s[4] = {};
#pragma unroll
    for (int c = 0; c < 2; c++) {
#pragma unroll
      for (int nt = 0; nt < 4; nt++) {
        int row = nt * 16 + lr;
        f16x8 kf = *(const f16x8*)(kbuf + row * 128 + (((c * 4 + lg) ^ (row & 7)) * 16));
        s[nt] = __builtin_amdgcn_mfma_f32_16x16x32_f16(aq[c], kf, s[nt], 0, 0, 0);
      }
    }
    // mask + online softmax; lane's rows are lg*4+r, col is lr within 16-tile nt
    float mx[4] = {-1e30f, -1e30f, -1e30f, -1e30f};
#pragma unroll
    for (int nt = 0; nt < 4; nt++) {
      int kpos = kstart + nt * 16 + lr;
#pragma unroll
      for (int r = 0; r < 4; r++) {
        int q = qbase + lg * 4 + r;
        int d = kpos - q;
        bool valid = ((unsigned)kpos < SL) && (d <= WIN) && (d >= -WIN);
        float sv = valid ? s[nt][r] : -1e30f;
        s[nt][r] = sv;
        mx[r] = fmaxf(mx[r], sv);
      }
    }
#pragma unroll
    for (int r = 0; r < 4; r++)
#pragma unroll
      for (int d = 1; d < 16; d <<= 1) mx[r] = fmaxf(mx[r], __shfl_xor(mx[r], d));
    float fac[4], rs[4];
#pragma unroll
    for (int r = 0; r < 4; r++) {
      float nm = fmaxf(m_[r], mx[r]);
      fac[r] = __expf(m_[r] - nm);
      m_[r] = nm;
      rs[r] = 0.f;
    }
#pragma unroll
    for (int nt = 0; nt < 4; nt++) {
#pragma unroll
      for (int r = 0; r < 4; r++) {
        float sv = s[nt][r];
        float p = (sv > -1e29f) ? __expf(sv - m_[r]) : 0.f;
        rs[r] += p;
        int q = lg * 4 + r;
        int bo2 = q * 128 + (((nt * 16 + lr) * 2) ^ ((q & 7) << 4));
        *(f16*)(pb + bo2) = (f16)p;
      }
    }
#pragma unroll
    for (int r = 0; r < 4; r++) {
#pragma unroll
      for (int d = 1; d < 16; d <<= 1) rs[r] += __shfl_xor(rs[r], d);
      l_[r] = l_[r] * fac[r] + rs[r];
    }
#pragma unroll
    for (int dt = 0; dt < 4; dt++)
#pragma unroll
      for (int r = 0; r < 4; r++) o[dt][r] *= fac[r];
    // O += P @ V   (per-wave P in LDS; V^T tile from LDS)
    const char* vbuf = (const char*)&Vs[cur][0];
#pragma unroll
    for (int c = 0; c < 2; c++) {
      f16x8 pa = *(const f16x8*)(pb + lr * 128 + ((c * 64 + lg * 16) ^ ((lr & 7) << 4)));
#pragma unroll
      for (int dt = 0; dt < 4; dt++) {
        int row = dt * 16 + lr;
        f16x8 vf = *(const f16x8*)(vbuf + row * 128 + (((c * 4 + lg) ^ (row & 7)) * 16));
        o[dt] = __builtin_amdgcn_mfma_f32_16x16x32_f16(pa, vf, o[dt], 0, 0, 0);
      }
    }
  }
  float rinv[4];
#pragma unroll
  for (int r = 0; r < 4; r++) rinv[r] = 1.f / l_[r];
#pragma unroll
  for (int dt = 0; dt < 4; dt++)
#pragma unroll
    for (int r = 0; r < 4; r++)
      ab[(size_t)(qbase + lg * 4 + r) * DM + h * 64 + dt * 16 + lr] = (f16)(o[dt][r] * rinv[r]);
}

// ---------------- launcher ----------------
extern "C" void kernel_launch(void* const* d_in, const int* in_sizes, int n_in,
                              void* d_out, int out_size, void* d_ws, size_t ws_size,
                              hipStream_t stream) {
  const int*   tokens  = (const int*)d_in[0];
  const float* emb_tok = (const float*)d_in[1];
  const float* emb_pos = (const float*)d_in[2];
  const float* ln_e_s  = (const float*)d_in[3];
  const float* ln_e_b  = (const float*)d_in[4];
  const float* Wq  = (const float*)d_in[5];
  const float* bq  = (const float*)d_in[6];
  const float* Wk  = (const float*)d_in[7];
  const float* bk  = (const float*)d_in[8];
  const float* Wv  = (const float*)d_in[9];
  const float* bv  = (const float*)d_in[10];
  const float* Wo  = (const float*)d_in[11];
  const float* bo  = (const float*)d_in[12];
  const float* ln1s = (const float*)d_in[13];
  const float* ln1b = (const float*)d_in[14];
  const float* W1f  = (const float*)d_in[15];
  const float* b1f  = (const float*)d_in[16];
  const float* W2f  = (const float*)d_in[17];
  const float* b2f  = (const float*)d_in[18];
  const float* ln2s = (const float*)d_in[19];
  const float* ln2b = (const float*)d_in[20];

  char* wsb = (char*)d_ws;
  float* x    = (float*)(wsb + 0);           // 12,582,912 B
  float* tb   = (float*)(wsb + 12582912);    // 12,582,912 B
  f16*   xh   = (f16*)  (wsb + 25165824);    //  6,291,456 B
  f16*   qkvh = (f16*)  (wsb + 31457280);    // 18,874,368 B  [3][NH][SL][64]
  f16*   vTh  = (f16*)  (wsb + 50331648);    //  6,291,456 B  [NH][64][SL]
  f16*   abf  = (f16*)  (wsb + 56623104);    //  6,291,456 B  [SL][DM]
  f16*   Wbuf = (f16*)  (wsb + 62914560);    //  4,718,592 B
  float* bqkv = (float*)(wsb + 67633152);    //     55,296 B
  f16*   hbuf = qkvh;                        // 25,165,824 B (reuses qkvh+vTh)
  f16*   qh = qkvh;
  f16*   kh = qkvh + (size_t)NH * HSZ;
  f16*   vh = qkvh + (size_t)2 * NH * HSZ;

  bias_fuse_kernel<<<(NL * QKVN + 255) / 256, 256, 0, stream>>>(bq, bk, bv, bqkv);
  embed_ln_kernel<<<SL, 256, 0, stream>>>(tokens, emb_tok, emb_pos, ln_e_s, ln_e_b, x, xh);

  dim3 t3(24, 24, 3), tW1(96, 24), tW2(24, 96);
  dim3 gqkv(QKVN / 128, SL / 128);  // (18,32)
  dim3 g768(DM / 64, SL / 128);     // (12,32) NF=2
  dim3 gffn(DFF / 128, SL / 128);   // (24,32)
  dim3 gvt(2, SL / 32, NH);         // (2,128,12)

  for (int lay = 0; lay < NL; lay++) {
    wtrans3_kernel<<<t3, 256, 0, stream>>>(Wq, Wk, Wv, Wbuf, lay);
    gemm_f16<0, 2, 4><<<gqkv, 256, 0, stream>>>(xh, Wbuf, bqkv + lay * QKVN, nullptr, qkvh, QKVN, DM);
    vtrans_kernel<<<gvt, 256, 0, stream>>>(vh, vTh);
    attn_f16<<<768, 256, 0, stream>>>(qh, kh, vTh, abf);
    wtrans_kernel<<<dim3(24, 24), 256, 0, stream>>>(Wo + (size_t)lay * DM * DM, Wbuf, DM, DM, 1.f);
    gemm_f16<0, 0, 2><<<g768, 256, 0, stream>>>(abf, Wbuf, bo + lay * DM, tb, nullptr, DM, DM);
    add_ln_kernel<<<SL, 256, 0, stream>>>(x, tb, ln1s + lay * DM, ln1b + lay * DM, x, xh);
    wtrans_kernel<<<tW1, 256, 0, stream>>>(W1f + (size_t)lay * DM * DFF, Wbuf, DM, DFF, 1.f);
    gemm_f16<1, 1, 4><<<gffn, 256, 0, stream>>>(xh, Wbuf, b1f + lay * DFF, nullptr, hbuf, DFF, DM);
    wtrans_kernel<<<tW2, 256, 0, stream>>>(W2f + (size_t)lay * DFF * DM, Wbuf, DFF, DM, 1.f);
    gemm_f16<0, 0, 2><<<g768, 256, 0, stream>>>(hbuf, Wbuf, b2f + lay * DM, tb, nullptr, DM, DFF);
    float* xo = (lay == NL - 1) ? (float*)d_out : x;
    add_ln_kernel<<<SL, 256, 0, stream>>>(x, tb, ln2s + lay * DM, ln2b + lay * DM, xo, xh);
  }
}